// Round 3
// baseline (81.826 us; speedup 1.0000x reference)
//
#include <hip/hip_runtime.h>

#define NB 32      // batch
#define NT 2048    // frames
#define ND 1024    // feature dim
#define NS 128     // max segments
#define CH 32      // frames per pooling chunk

// ---------------------------------------------------------------------------
// Kernel Z: zero the pooled output region (atomics accumulate into it)
// ---------------------------------------------------------------------------
__global__ __launch_bounds__(256)
void zero_kernel(float4* __restrict__ p) {
    p[(size_t)blockIdx.x * 256 + threadIdx.x] = make_float4(0.f, 0.f, 0.f, 0.f);
}

// ---------------------------------------------------------------------------
// Kernel A: per-batch boundary scan -> per-frame seg id, inv count, out1, out2
// grid = NB blocks, 256 threads
// ---------------------------------------------------------------------------
__global__ __launch_bounds__(256)
void seg_scan_kernel(const int* __restrict__ in_boundary,  // [NB, NT+1]
                     int* __restrict__ sid,                // [NB, NT]  ws
                     float* __restrict__ inv_ws,           // [NB, NS]  ws
                     float* __restrict__ out1,             // [NB, NS]
                     float* __restrict__ out2)             // [NB, NT+1]
{
    const int b   = blockIdx.x;
    const int tid = threadIdx.x;              // 256 threads
    const int* bd = in_boundary + (size_t)b * (NT + 1);

    __shared__ int thr_sum[256];
    __shared__ int starts[NS + 1];

    for (int s = tid; s <= NS; s += 256) starts[s] = NT;  // default: no segment
    __syncthreads();

    // each thread scans 8 consecutive frames
    const int t0 = tid * 8;
    int v[8];
    int local = 0;
#pragma unroll
    for (int j = 0; j < 8; ++j) {
        int t = t0 + j;
        int bit = (t == 0) ? 1 : bd[t];       // force boundary at frame 0
        v[j] = bit;
        local += bit;
    }
    thr_sum[tid] = local;
    __syncthreads();

    // Hillis-Steele inclusive scan across 256 thread sums
    for (int off = 1; off < 256; off <<= 1) {
        int val = thr_sum[tid];
        int add = (tid >= off) ? thr_sum[tid - off] : 0;
        __syncthreads();
        thr_sum[tid] = val + add;
        __syncthreads();
    }
    const int excl = thr_sum[tid] - local;    // boundaries strictly before t0

    // record segment starts + per-frame segment id
    int run = excl;
#pragma unroll
    for (int j = 0; j < 8; ++j) {
        run += v[j];
        int seg = run - 1;                    // seg id of frame t0+j
        sid[(size_t)b * NT + t0 + j] = seg;
        if (v[j] && seg <= NS) starts[seg] = t0 + j;
    }
    __syncthreads();

    if (tid < NS) {
        int st = starts[tid];
        int c  = starts[tid + 1] - st;        // 0 for non-existent segments
        inv_ws[b * NS + tid] = (c > 0) ? 1.0f / (float)c : 0.0f;
        out1[b * NS + tid]   = (c > 0) ? 1.0f : 0.0f;
    }

    // passthrough of raw in_boundary as float
    for (int t = tid; t <= NT; t += 256)
        out2[(size_t)b * (NT + 1) + t] = (float)bd[t];
}

// ---------------------------------------------------------------------------
// Kernel B: uniform-work pooling. Each block owns 32 contiguous frames of one
// batch row, accumulates per-segment partials (pre-scaled by 1/count) and
// atomically adds them into pooled. grid = (NT/CH, NB), 256 threads.
// ---------------------------------------------------------------------------
__global__ __launch_bounds__(256)
void pool_kernel(const float* __restrict__ x,          // [NB, NT, ND]
                 const int* __restrict__ sid,          // [NB, NT]
                 const float* __restrict__ inv_ws,     // [NB, NS]
                 float* __restrict__ pooled)           // [NB, NS, ND]
{
    const int chunk = blockIdx.x;             // 0 .. NT/CH-1
    const int b     = blockIdx.y;
    const int tid   = threadIdx.x;            // 256 -> ND/4 float4 lanes
    const int t0    = chunk * CH;

    __shared__ int sid_l[CH];
    if (tid < CH) sid_l[tid] = sid[(size_t)b * NT + t0 + tid];
    __syncthreads();

    const float4* xp = (const float4*)(x + (size_t)b * NT * ND) + tid;

    float4 acc = make_float4(0.f, 0.f, 0.f, 0.f);
    int cur = sid_l[0];

    auto flush = [&](int seg, const float4& a) {
        if (seg < NS) {
            float sc = inv_ws[b * NS + seg];
            float* dst = pooled + ((size_t)b * NS + seg) * ND + tid * 4;
            atomicAdd(dst + 0, a.x * sc);
            atomicAdd(dst + 1, a.y * sc);
            atomicAdd(dst + 2, a.z * sc);
            atomicAdd(dst + 3, a.w * sc);
        }
    };

    for (int g = 0; g < CH / 8; ++g) {
        float4 v[8];
#pragma unroll
        for (int j = 0; j < 8; ++j)
            v[j] = xp[(size_t)(t0 + g * 8 + j) * (ND / 4)];
#pragma unroll
        for (int j = 0; j < 8; ++j) {
            int sg = sid_l[g * 8 + j];        // uniform across block
            if (sg != cur) {                  // uniform branch, rare
                flush(cur, acc);
                acc = make_float4(0.f, 0.f, 0.f, 0.f);
                cur = sg;
            }
            acc.x += v[j].x; acc.y += v[j].y; acc.z += v[j].z; acc.w += v[j].w;
        }
    }
    flush(cur, acc);
}

// ---------------------------------------------------------------------------
extern "C" void kernel_launch(void* const* d_in, const int* in_sizes, int n_in,
                              void* d_out, int out_size, void* d_ws, size_t ws_size,
                              hipStream_t stream) {
    const float* x           = (const float*)d_in[0];       // [NB, NT, ND]
    const int*   in_boundary = (const int*)d_in[1];         // [NB, NT+1]

    float* pooled = (float*)d_out;                          // [NB, NS, ND]
    float* out1   = pooled + (size_t)NB * NS * ND;          // [NB, NS]
    float* out2   = out1 + (size_t)NB * NS;                 // [NB, NT+1]

    int*   sid    = (int*)d_ws;                             // [NB, NT]
    float* inv_ws = (float*)(sid + (size_t)NB * NT);        // [NB, NS]

    // zero pooled (NB*NS*ND floats = 1,048,576 float4s -> 4096 blocks)
    zero_kernel<<<(NB * NS * ND / 4) / 256, 256, 0, stream>>>((float4*)pooled);

    seg_scan_kernel<<<NB, 256, 0, stream>>>(in_boundary, sid, inv_ws, out1, out2);

    pool_kernel<<<dim3(NT / CH, NB), 256, 0, stream>>>(x, sid, inv_ws, pooled);
}

// Round 4
// 65.517 us; speedup vs baseline: 1.2489x; 1.2489x over previous
//
#include <hip/hip_runtime.h>

#define NB 32      // batch
#define NT 2048    // frames
#define ND 1024    // feature dim
#define NS 128     // max segments

// ---------------------------------------------------------------------------
// Kernel A: per-batch boundary scan -> segment start/count, out1, out2
// grid = NB blocks, 256 threads. Wave-level shfl scan: 2 barriers total.
// ---------------------------------------------------------------------------
__global__ __launch_bounds__(256)
void seg_scan_kernel(const int* __restrict__ in_boundary,  // [NB, NT+1]
                     int* __restrict__ seg_start,          // [NB, NS]
                     int* __restrict__ seg_count,          // [NB, NS]
                     float* __restrict__ out1,             // [NB, NS]
                     float* __restrict__ out2)             // [NB, NT+1]
{
    const int b    = blockIdx.x;
    const int tid  = threadIdx.x;             // 256 threads = 4 waves
    const int lane = tid & 63;
    const int wid  = tid >> 6;
    const int* bd  = in_boundary + (size_t)b * (NT + 1);

    __shared__ int starts[NS + 1];
    __shared__ int wtot[4];

    for (int s = tid; s <= NS; s += 256) starts[s] = NT;  // default: no segment

    // each thread scans 8 consecutive frames
    const int t0 = tid * 8;
    int v[8];
    int local = 0;
#pragma unroll
    for (int j = 0; j < 8; ++j) {
        int t = t0 + j;
        int bit = (t == 0) ? 1 : bd[t];       // force boundary at frame 0
        v[j] = bit;
        local += bit;
    }

    // 64-lane inclusive scan of per-thread sums (no barriers)
    int incl = local;
#pragma unroll
    for (int off = 1; off < 64; off <<= 1) {
        int n = __shfl_up(incl, off, 64);
        if (lane >= off) incl += n;
    }
    if (lane == 63) wtot[wid] = incl;         // wave total
    __syncthreads();

    int wpref = 0;
#pragma unroll
    for (int w = 0; w < 4; ++w)
        if (w < wid) wpref += wtot[w];
    const int excl = wpref + incl - local;    // boundaries strictly before t0

    // record segment starts (each segment start written by exactly one lane)
    int run = excl;
#pragma unroll
    for (int j = 0; j < 8; ++j) {
        run += v[j];
        int seg = run - 1;                    // seg id of frame t0+j
        if (v[j] && seg <= NS) starts[seg] = t0 + j;
    }
    __syncthreads();

    if (tid < NS) {
        int st = starts[tid];
        int c  = starts[tid + 1] - st;        // 0 for non-existent segments
        seg_start[b * NS + tid] = st;
        seg_count[b * NS + tid] = c;
        out1[b * NS + tid] = (c > 0) ? 1.0f : 0.0f;
    }

    // passthrough of raw in_boundary as float
    for (int t = tid; t <= NT; t += 256)
        out2[(size_t)b * (NT + 1) + t] = (float)bd[t];
}

// ---------------------------------------------------------------------------
// Kernel B: segment mean pooling, 8-deep unrolled for memory-level parallelism
// grid = (NS, NB), 256 threads, each thread owns one float4 of D
// ---------------------------------------------------------------------------
__global__ __launch_bounds__(256)
void pool_kernel(const float* __restrict__ x,          // [NB, NT, ND]
                 const int* __restrict__ seg_start,    // [NB, NS]
                 const int* __restrict__ seg_count,    // [NB, NS]
                 float* __restrict__ pooled)           // [NB, NS, ND]
{
    const int s   = blockIdx.x;
    const int b   = blockIdx.y;
    const int tid = threadIdx.x;              // 256 -> ND/4 float4 lanes

    const int st = seg_start[b * NS + s];
    const int c  = seg_count[b * NS + s];

    const float4* xp = (const float4*)(x + (size_t)b * NT * ND) + tid;

    float4 a0 = make_float4(0.f,0.f,0.f,0.f);
    float4 a1 = make_float4(0.f,0.f,0.f,0.f);
    float4 a2 = make_float4(0.f,0.f,0.f,0.f);
    float4 a3 = make_float4(0.f,0.f,0.f,0.f);

    const int end = st + c;
    int t = st;

    // 8 independent float4 loads in flight
    for (; t + 8 <= end; t += 8) {
        float4 v0 = xp[(size_t)(t + 0) * (ND / 4)];
        float4 v1 = xp[(size_t)(t + 1) * (ND / 4)];
        float4 v2 = xp[(size_t)(t + 2) * (ND / 4)];
        float4 v3 = xp[(size_t)(t + 3) * (ND / 4)];
        float4 v4 = xp[(size_t)(t + 4) * (ND / 4)];
        float4 v5 = xp[(size_t)(t + 5) * (ND / 4)];
        float4 v6 = xp[(size_t)(t + 6) * (ND / 4)];
        float4 v7 = xp[(size_t)(t + 7) * (ND / 4)];
        a0.x += v0.x; a0.y += v0.y; a0.z += v0.z; a0.w += v0.w;
        a1.x += v1.x; a1.y += v1.y; a1.z += v1.z; a1.w += v1.w;
        a2.x += v2.x; a2.y += v2.y; a2.z += v2.z; a2.w += v2.w;
        a3.x += v3.x; a3.y += v3.y; a3.z += v3.z; a3.w += v3.w;
        a0.x += v4.x; a0.y += v4.y; a0.z += v4.z; a0.w += v4.w;
        a1.x += v5.x; a1.y += v5.y; a1.z += v5.z; a1.w += v5.w;
        a2.x += v6.x; a2.y += v6.y; a2.z += v6.z; a2.w += v6.w;
        a3.x += v7.x; a3.y += v7.y; a3.z += v7.z; a3.w += v7.w;
    }
    // 4-deep tail (keeps MLP for short segments)
    if (t + 4 <= end) {
        float4 v0 = xp[(size_t)(t + 0) * (ND / 4)];
        float4 v1 = xp[(size_t)(t + 1) * (ND / 4)];
        float4 v2 = xp[(size_t)(t + 2) * (ND / 4)];
        float4 v3 = xp[(size_t)(t + 3) * (ND / 4)];
        a0.x += v0.x; a0.y += v0.y; a0.z += v0.z; a0.w += v0.w;
        a1.x += v1.x; a1.y += v1.y; a1.z += v1.z; a1.w += v1.w;
        a2.x += v2.x; a2.y += v2.y; a2.z += v2.z; a2.w += v2.w;
        a3.x += v3.x; a3.y += v3.y; a3.z += v3.z; a3.w += v3.w;
        t += 4;
    }
    for (; t < end; ++t) {
        float4 v0 = xp[(size_t)t * (ND / 4)];
        a0.x += v0.x; a0.y += v0.y; a0.z += v0.z; a0.w += v0.w;
    }

    a0.x += a1.x + a2.x + a3.x;
    a0.y += a1.y + a2.y + a3.y;
    a0.z += a1.z + a2.z + a3.z;
    a0.w += a1.w + a2.w + a3.w;

    const float inv = (c > 0) ? 1.0f / (float)c : 0.0f;
    a0.x *= inv; a0.y *= inv; a0.z *= inv; a0.w *= inv;

    ((float4*)pooled)[((size_t)b * NS + s) * (ND / 4) + tid] = a0;
}

// ---------------------------------------------------------------------------
extern "C" void kernel_launch(void* const* d_in, const int* in_sizes, int n_in,
                              void* d_out, int out_size, void* d_ws, size_t ws_size,
                              hipStream_t stream) {
    const float* x           = (const float*)d_in[0];       // [NB, NT, ND]
    const int*   in_boundary = (const int*)d_in[1];         // [NB, NT+1]

    float* pooled = (float*)d_out;                          // [NB, NS, ND]
    float* out1   = pooled + (size_t)NB * NS * ND;          // [NB, NS]
    float* out2   = out1 + (size_t)NB * NS;                 // [NB, NT+1]

    int* seg_start = (int*)d_ws;                            // [NB, NS]
    int* seg_count = seg_start + NB * NS;                   // [NB, NS]

    seg_scan_kernel<<<NB, 256, 0, stream>>>(in_boundary, seg_start, seg_count,
                                            out1, out2);
    pool_kernel<<<dim3(NS, NB), 256, 0, stream>>>(x, seg_start, seg_count, pooled);
}

// Round 5
// 57.985 us; speedup vs baseline: 1.4112x; 1.1299x over previous
//
#include <hip/hip_runtime.h>

#define NB 32      // batch
#define NT 2048    // frames
#define ND 1024    // feature dim
#define NS 128     // max segments
#define CH 32      // frames per chunk
#define NQ (NT / CH)  // 64 chunks per batch row

// ---------------------------------------------------------------------------
// Kernel A: per-batch boundary scan -> per-frame seg id, seg start/count,
// out1, out2. grid = NB blocks, 256 threads. shfl scan, 2 barriers.
// ---------------------------------------------------------------------------
__global__ __launch_bounds__(256)
void seg_scan_kernel(const int* __restrict__ in_boundary,  // [NB, NT+1]
                     int* __restrict__ sid,                // [NB, NT]   ws
                     int* __restrict__ seg_start,          // [NB, NS]   ws
                     int* __restrict__ seg_count,          // [NB, NS]   ws
                     float* __restrict__ out1,             // [NB, NS]
                     float* __restrict__ out2)             // [NB, NT+1]
{
    const int b    = blockIdx.x;
    const int tid  = threadIdx.x;             // 256 threads = 4 waves
    const int lane = tid & 63;
    const int wid  = tid >> 6;
    const int* bd  = in_boundary + (size_t)b * (NT + 1);

    __shared__ int starts[NS + 1];
    __shared__ int wtot[4];

    for (int s = tid; s <= NS; s += 256) starts[s] = NT;  // default: no segment

    // each thread scans 8 consecutive frames
    const int t0 = tid * 8;
    int v[8];
    int local = 0;
#pragma unroll
    for (int j = 0; j < 8; ++j) {
        int t = t0 + j;
        int bit = (t == 0) ? 1 : bd[t];       // force boundary at frame 0
        v[j] = bit;
        local += bit;
    }

    // 64-lane inclusive scan of per-thread sums
    int incl = local;
#pragma unroll
    for (int off = 1; off < 64; off <<= 1) {
        int n = __shfl_up(incl, off, 64);
        if (lane >= off) incl += n;
    }
    if (lane == 63) wtot[wid] = incl;         // wave total
    __syncthreads();

    int wpref = 0;
#pragma unroll
    for (int w = 0; w < 4; ++w)
        if (w < wid) wpref += wtot[w];
    const int excl = wpref + incl - local;    // boundaries strictly before t0

    // per-frame seg id + segment starts
    int run = excl;
#pragma unroll
    for (int j = 0; j < 8; ++j) {
        run += v[j];
        int seg = run - 1;                    // seg id of frame t0+j
        sid[(size_t)b * NT + t0 + j] = seg;
        if (v[j] && seg <= NS) starts[seg] = t0 + j;
    }
    __syncthreads();

    if (tid < NS) {
        int st = starts[tid];
        int c  = starts[tid + 1] - st;        // 0 for non-existent segments
        seg_start[b * NS + tid] = st;
        seg_count[b * NS + tid] = c;
        out1[b * NS + tid] = (c > 0) ? 1.0f : 0.0f;
    }

    // passthrough of raw in_boundary as float
    for (int t = tid; t <= NT; t += 256)
        out2[(size_t)b * (NT + 1) + t] = (float)bd[t];
}

// ---------------------------------------------------------------------------
// Kernel B: uniform chunked pooling. Each block reads exactly CH contiguous
// frames. Fully-contained segments -> final scaled write to pooled (sole
// owner). Edge-crossing segments (<=2 per chunk) -> unscaled partial to ws.
// grid = (NQ, NB), 256 threads.
// ---------------------------------------------------------------------------
__global__ __launch_bounds__(256)
void pool_chunk_kernel(const float* __restrict__ x,          // [NB, NT, ND]
                       const int* __restrict__ sid,          // [NB, NT]
                       const int* __restrict__ seg_start,    // [NB, NS]
                       const int* __restrict__ seg_count,    // [NB, NS]
                       float* __restrict__ partial,          // [NB, NQ, 2, ND]
                       float* __restrict__ pooled)           // [NB, NS, ND]
{
    const int q   = blockIdx.x;
    const int b   = blockIdx.y;
    const int tid = threadIdx.x;              // 256 -> ND/4 float4 lanes
    const int t0  = q * CH;

    __shared__ int sid_l[CH];
    if (tid < CH) sid_l[tid] = sid[(size_t)b * NT + t0 + tid];
    __syncthreads();
    const int s_first = sid_l[0];

    const float4* xp = (const float4*)(x + (size_t)b * NT * ND) + tid;

    float4 acc = make_float4(0.f, 0.f, 0.f, 0.f);
    int cur = s_first;

    auto flush = [&](int seg, const float4& a) {
        if (seg >= NS) return;
        const int st = seg_start[b * NS + seg];
        const int c  = seg_count[b * NS + seg];
        if (st >= t0 && st + c <= t0 + CH) {
            // fully contained in this chunk: final scaled write, sole owner
            const float inv = 1.0f / (float)c;
            ((float4*)pooled)[((size_t)b * NS + seg) * (ND / 4) + tid] =
                make_float4(a.x * inv, a.y * inv, a.z * inv, a.w * inv);
        } else {
            // crossing segment: head partial -> slot 0, tail partial -> slot 1
            const int slot = (seg == s_first) ? 0 : 1;
            ((float4*)partial)[(((size_t)b * NQ + q) * 2 + slot) * (ND / 4) + tid] = a;
        }
    };

    for (int g = 0; g < CH / 8; ++g) {
        float4 v[8];
#pragma unroll
        for (int j = 0; j < 8; ++j)
            v[j] = xp[(size_t)(t0 + g * 8 + j) * (ND / 4)];
#pragma unroll
        for (int j = 0; j < 8; ++j) {
            int sg = sid_l[g * 8 + j];        // uniform across block
            if (sg != cur) {                  // uniform branch, rare
                flush(cur, acc);
                acc = make_float4(0.f, 0.f, 0.f, 0.f);
                cur = sg;
            }
            acc.x += v[j].x; acc.y += v[j].y; acc.z += v[j].z; acc.w += v[j].w;
        }
    }
    flush(cur, acc);
}

// ---------------------------------------------------------------------------
// Kernel C: combine crossing-segment partials; zero empty rows.
// grid = (NS, NB), 256 threads.
// ---------------------------------------------------------------------------
__global__ __launch_bounds__(256)
void combine_kernel(const int* __restrict__ seg_start,    // [NB, NS]
                    const int* __restrict__ seg_count,    // [NB, NS]
                    const float* __restrict__ partial,    // [NB, NQ, 2, ND]
                    float* __restrict__ pooled)           // [NB, NS, ND]
{
    const int s   = blockIdx.x;
    const int b   = blockIdx.y;
    const int tid = threadIdx.x;

    const int st = seg_start[b * NS + s];
    const int c  = seg_count[b * NS + s];
    float4* out = (float4*)pooled + ((size_t)b * NS + s) * (ND / 4) + tid;

    if (c <= 0) {                             // empty segment: zero the row
        *out = make_float4(0.f, 0.f, 0.f, 0.f);
        return;
    }
    const int q0 = st / CH;
    const int q1 = (st + c - 1) / CH;
    if (q0 == q1) return;                     // written by its chunk already

    const float4* pp = (const float4*)partial + tid;
    const int slot0 = (st == q0 * CH) ? 0 : 1;
    float4 a = pp[(((size_t)b * NQ + q0) * 2 + slot0) * (ND / 4)];
    for (int q = q0 + 1; q <= q1; ++q) {
        float4 v = pp[(((size_t)b * NQ + q) * 2 + 0) * (ND / 4)];
        a.x += v.x; a.y += v.y; a.z += v.z; a.w += v.w;
    }
    const float inv = 1.0f / (float)c;
    *out = make_float4(a.x * inv, a.y * inv, a.z * inv, a.w * inv);
}

// ---------------------------------------------------------------------------
extern "C" void kernel_launch(void* const* d_in, const int* in_sizes, int n_in,
                              void* d_out, int out_size, void* d_ws, size_t ws_size,
                              hipStream_t stream) {
    const float* x           = (const float*)d_in[0];       // [NB, NT, ND]
    const int*   in_boundary = (const int*)d_in[1];         // [NB, NT+1]

    float* pooled = (float*)d_out;                          // [NB, NS, ND]
    float* out1   = pooled + (size_t)NB * NS * ND;          // [NB, NS]
    float* out2   = out1 + (size_t)NB * NS;                 // [NB, NT+1]

    int*   sid       = (int*)d_ws;                          // [NB, NT]
    int*   seg_start = sid + (size_t)NB * NT;               // [NB, NS]
    int*   seg_count = seg_start + NB * NS;                 // [NB, NS]
    float* partial   = (float*)(seg_count + NB * NS);       // [NB, NQ, 2, ND]

    seg_scan_kernel<<<NB, 256, 0, stream>>>(in_boundary, sid, seg_start,
                                            seg_count, out1, out2);
    pool_chunk_kernel<<<dim3(NQ, NB), 256, 0, stream>>>(x, sid, seg_start,
                                                        seg_count, partial, pooled);
    combine_kernel<<<dim3(NS, NB), 256, 0, stream>>>(seg_start, seg_count,
                                                     partial, pooled);
}

// Round 7
// 56.299 us; speedup vs baseline: 1.4534x; 1.0299x over previous
//
#include <hip/hip_runtime.h>

#define NB 32      // batch
#define NT 2048    // frames
#define ND 1024    // feature dim
#define NS 128     // max segments
#define CH 64      // frames per chunk
#define NQ (NT / CH)  // 32 chunks per batch row

typedef float f32x4 __attribute__((ext_vector_type(4)));  // clang-native vec4

__device__ __forceinline__ void nt_store4(float* p, float a, float b, float c, float d) {
    f32x4 v = {a, b, c, d};
    __builtin_nontemporal_store(v, (f32x4*)p);
}

// ---------------------------------------------------------------------------
// Kernel A: per-batch boundary scan -> per-frame seg id, seg start/count,
// out1, out2. grid = NB blocks, 256 threads. shfl scan, 2 barriers.
// ---------------------------------------------------------------------------
__global__ __launch_bounds__(256)
void seg_scan_kernel(const int* __restrict__ in_boundary,  // [NB, NT+1]
                     int* __restrict__ sid,                // [NB, NT]   ws
                     int* __restrict__ seg_start,          // [NB, NS]   ws
                     int* __restrict__ seg_count,          // [NB, NS]   ws
                     float* __restrict__ out1,             // [NB, NS]
                     float* __restrict__ out2)             // [NB, NT+1]
{
    const int b    = blockIdx.x;
    const int tid  = threadIdx.x;             // 256 threads = 4 waves
    const int lane = tid & 63;
    const int wid  = tid >> 6;
    const int* bd  = in_boundary + (size_t)b * (NT + 1);

    __shared__ int starts[NS + 1];
    __shared__ int wtot[4];

    for (int s = tid; s <= NS; s += 256) starts[s] = NT;  // default: no segment

    // each thread scans 8 consecutive frames
    const int t0 = tid * 8;
    int v[8];
    int local = 0;
#pragma unroll
    for (int j = 0; j < 8; ++j) {
        int t = t0 + j;
        int bit = (t == 0) ? 1 : bd[t];       // force boundary at frame 0
        v[j] = bit;
        local += bit;
    }

    // 64-lane inclusive scan of per-thread sums
    int incl = local;
#pragma unroll
    for (int off = 1; off < 64; off <<= 1) {
        int n = __shfl_up(incl, off, 64);
        if (lane >= off) incl += n;
    }
    if (lane == 63) wtot[wid] = incl;         // wave total
    __syncthreads();

    int wpref = 0;
#pragma unroll
    for (int w = 0; w < 4; ++w)
        if (w < wid) wpref += wtot[w];
    const int excl = wpref + incl - local;    // boundaries strictly before t0

    // per-frame seg id + segment starts
    int run = excl;
#pragma unroll
    for (int j = 0; j < 8; ++j) {
        run += v[j];
        int seg = run - 1;                    // seg id of frame t0+j
        sid[(size_t)b * NT + t0 + j] = seg;
        if (v[j] && seg <= NS) starts[seg] = t0 + j;
    }
    __syncthreads();

    if (tid < NS) {
        int st = starts[tid];
        int c  = starts[tid + 1] - st;        // 0 for non-existent segments
        seg_start[b * NS + tid] = st;
        seg_count[b * NS + tid] = c;
        out1[b * NS + tid] = (c > 0) ? 1.0f : 0.0f;
    }

    // passthrough of raw in_boundary as float
    for (int t = tid; t <= NT; t += 256)
        out2[(size_t)b * (NT + 1) + t] = (float)bd[t];
}

// ---------------------------------------------------------------------------
// Kernel B: uniform chunked pooling. Each block reads exactly CH contiguous
// frames. Fully-contained segments -> final scaled write to pooled (sole
// owner, nontemporal). Edge-crossing segments (<=2 per chunk) -> unscaled
// partial to ws. grid = (NQ, NB), 256 threads.
// ---------------------------------------------------------------------------
__global__ __launch_bounds__(256)
void pool_chunk_kernel(const float* __restrict__ x,          // [NB, NT, ND]
                       const int* __restrict__ sid,          // [NB, NT]
                       const int* __restrict__ seg_start,    // [NB, NS]
                       const int* __restrict__ seg_count,    // [NB, NS]
                       float* __restrict__ partial,          // [NB, NQ, 2, ND]
                       float* __restrict__ pooled)           // [NB, NS, ND]
{
    const int q   = blockIdx.x;
    const int b   = blockIdx.y;
    const int tid = threadIdx.x;              // 256 -> ND/4 float4 lanes
    const int t0  = q * CH;

    __shared__ int sid_l[CH];
    if (tid < CH) sid_l[tid] = sid[(size_t)b * NT + t0 + tid];
    __syncthreads();
    const int s_first = sid_l[0];

    const float4* xp = (const float4*)(x + (size_t)b * NT * ND) + tid;

    float4 acc = make_float4(0.f, 0.f, 0.f, 0.f);
    int cur = s_first;

    auto flush = [&](int seg, const float4& a) {
        if (seg >= NS) return;
        const int st = seg_start[b * NS + seg];
        const int c  = seg_count[b * NS + seg];
        if (st >= t0 && st + c <= t0 + CH) {
            // fully contained in this chunk: final scaled write, sole owner
            const float inv = 1.0f / (float)c;
            nt_store4(pooled + ((size_t)b * NS + seg) * ND + tid * 4,
                      a.x * inv, a.y * inv, a.z * inv, a.w * inv);
        } else {
            // crossing segment: head partial -> slot 0, tail partial -> slot 1
            const int slot = (seg == s_first) ? 0 : 1;
            ((float4*)partial)[(((size_t)b * NQ + q) * 2 + slot) * (ND / 4) + tid] = a;
        }
    };

    for (int g = 0; g < CH / 8; ++g) {
        float4 v[8];
#pragma unroll
        for (int j = 0; j < 8; ++j)
            v[j] = xp[(size_t)(t0 + g * 8 + j) * (ND / 4)];
#pragma unroll
        for (int j = 0; j < 8; ++j) {
            int sg = sid_l[g * 8 + j];        // uniform across block
            if (sg != cur) {                  // uniform branch, rare
                flush(cur, acc);
                acc = make_float4(0.f, 0.f, 0.f, 0.f);
                cur = sg;
            }
            acc.x += v[j].x; acc.y += v[j].y; acc.z += v[j].z; acc.w += v[j].w;
        }
    }
    flush(cur, acc);
}

// ---------------------------------------------------------------------------
// Kernel C: combine crossing-segment partials; zero empty rows.
// grid = (NS, NB), 256 threads.
// ---------------------------------------------------------------------------
__global__ __launch_bounds__(256)
void combine_kernel(const int* __restrict__ seg_start,    // [NB, NS]
                    const int* __restrict__ seg_count,    // [NB, NS]
                    const float* __restrict__ partial,    // [NB, NQ, 2, ND]
                    float* __restrict__ pooled)           // [NB, NS, ND]
{
    const int s   = blockIdx.x;
    const int b   = blockIdx.y;
    const int tid = threadIdx.x;

    const int st = seg_start[b * NS + s];
    const int c  = seg_count[b * NS + s];
    float* out = pooled + ((size_t)b * NS + s) * ND + tid * 4;

    if (c <= 0) {                             // empty segment: zero the row
        nt_store4(out, 0.f, 0.f, 0.f, 0.f);
        return;
    }
    const int q0 = st / CH;
    const int q1 = (st + c - 1) / CH;
    if (q0 == q1) return;                     // written by its chunk already

    const float4* pp = (const float4*)partial + tid;
    const int slot0 = (st == q0 * CH) ? 0 : 1;
    float4 a = pp[(((size_t)b * NQ + q0) * 2 + slot0) * (ND / 4)];
    for (int q = q0 + 1; q <= q1; ++q) {
        float4 v = pp[(((size_t)b * NQ + q) * 2 + 0) * (ND / 4)];
        a.x += v.x; a.y += v.y; a.z += v.z; a.w += v.w;
    }
    const float inv = 1.0f / (float)c;
    nt_store4(out, a.x * inv, a.y * inv, a.z * inv, a.w * inv);
}

// ---------------------------------------------------------------------------
extern "C" void kernel_launch(void* const* d_in, const int* in_sizes, int n_in,
                              void* d_out, int out_size, void* d_ws, size_t ws_size,
                              hipStream_t stream) {
    const float* x           = (const float*)d_in[0];       // [NB, NT, ND]
    const int*   in_boundary = (const int*)d_in[1];         // [NB, NT+1]

    float* pooled = (float*)d_out;                          // [NB, NS, ND]
    float* out1   = pooled + (size_t)NB * NS * ND;          // [NB, NS]
    float* out2   = out1 + (size_t)NB * NS;                 // [NB, NT+1]

    int*   sid       = (int*)d_ws;                          // [NB, NT]
    int*   seg_start = sid + (size_t)NB * NT;               // [NB, NS]
    int*   seg_count = seg_start + NB * NS;                 // [NB, NS]
    float* partial   = (float*)(seg_count + NB * NS);       // [NB, NQ, 2, ND]

    seg_scan_kernel<<<NB, 256, 0, stream>>>(in_boundary, sid, seg_start,
                                            seg_count, out1, out2);
    pool_chunk_kernel<<<dim3(NQ, NB), 256, 0, stream>>>(x, sid, seg_start,
                                                        seg_count, partial, pooled);
    combine_kernel<<<dim3(NS, NB), 256, 0, stream>>>(seg_start, seg_count,
                                                     partial, pooled);
}

// Round 8
// 51.395 us; speedup vs baseline: 1.5921x; 1.0954x over previous
//
#include <hip/hip_runtime.h>

#define NB 32      // batch
#define NT 2048    // frames
#define ND 1024    // feature dim
#define NS 128     // max segments
#define CH 64      // frames per chunk
#define NQ (NT / CH)  // 32 chunks per batch row

typedef float f32x4 __attribute__((ext_vector_type(4)));  // clang-native vec4

__device__ __forceinline__ void nt_store4(float* p, float a, float b, float c, float d) {
    f32x4 v = {a, b, c, d};
    __builtin_nontemporal_store(v, (f32x4*)p);
}

// ---------------------------------------------------------------------------
// Fused kernel: every block recomputes the (cheap, 8 KB, L2-broadcast)
// boundary scan for its batch row, then pools its own CH-frame chunk.
// Fully-contained segments -> final scaled nontemporal write (sole owner).
// Edge-crossing segments -> unscaled partial to ws. q==0 blocks also emit
// out1/out2 and persist seg_start/count for the combine pass.
// grid = (NQ, NB), 256 threads.
// ---------------------------------------------------------------------------
__global__ __launch_bounds__(256)
void fused_pool_kernel(const float* __restrict__ x,           // [NB, NT, ND]
                       const int* __restrict__ in_boundary,   // [NB, NT+1]
                       int* __restrict__ seg_start_ws,        // [NB, NS]
                       int* __restrict__ seg_count_ws,        // [NB, NS]
                       float* __restrict__ partial,           // [NB, NQ, 2, ND]
                       float* __restrict__ pooled,            // [NB, NS, ND]
                       float* __restrict__ out1,              // [NB, NS]
                       float* __restrict__ out2)              // [NB, NT+1]
{
    const int q    = blockIdx.x;
    const int b    = blockIdx.y;
    const int tid  = threadIdx.x;             // 256 threads = 4 waves
    const int lane = tid & 63;
    const int wid  = tid >> 6;
    const int t0   = q * CH;
    const int* bd  = in_boundary + (size_t)b * (NT + 1);

    const float4* xp = (const float4*)(x + (size_t)b * NT * ND) + tid;

    // ---- prefetch x group 0 (8 frames) so scan latency hides under it ----
    float4 p0 = xp[(size_t)(t0 + 0) * (ND / 4)];
    float4 p1 = xp[(size_t)(t0 + 1) * (ND / 4)];
    float4 p2 = xp[(size_t)(t0 + 2) * (ND / 4)];
    float4 p3 = xp[(size_t)(t0 + 3) * (ND / 4)];
    float4 p4 = xp[(size_t)(t0 + 4) * (ND / 4)];
    float4 p5 = xp[(size_t)(t0 + 5) * (ND / 4)];
    float4 p6 = xp[(size_t)(t0 + 6) * (ND / 4)];
    float4 p7 = xp[(size_t)(t0 + 7) * (ND / 4)];

    __shared__ int starts[NS + 1];
    __shared__ int wtot[4];
    __shared__ int sid_all[NT];

    for (int s = tid; s <= NS; s += 256) starts[s] = NT;  // default: no segment

    // ---- full-row boundary scan (thread tid owns frames tid*8..tid*8+7) ----
    const int f0 = tid * 8;
    int bv[8];
    int local = 0;
#pragma unroll
    for (int j = 0; j < 8; ++j) {
        int t = f0 + j;
        int bit = (t == 0) ? 1 : bd[t];       // force boundary at frame 0
        bv[j] = bit;
        local += bit;
    }

    int incl = local;
#pragma unroll
    for (int off = 1; off < 64; off <<= 1) {
        int n = __shfl_up(incl, off, 64);
        if (lane >= off) incl += n;
    }
    if (lane == 63) wtot[wid] = incl;
    __syncthreads();

    int wpref = 0;
#pragma unroll
    for (int w = 0; w < 4; ++w)
        if (w < wid) wpref += wtot[w];
    const int excl = wpref + incl - local;

    int run = excl;
#pragma unroll
    for (int j = 0; j < 8; ++j) {
        run += bv[j];
        int seg = run - 1;
        sid_all[f0 + j] = seg;
        if (bv[j] && seg <= NS) starts[seg] = f0 + j;
    }
    __syncthreads();

    // ---- q==0 blocks emit scalar outputs + ws tables for combine ----
    if (q == 0) {
        if (tid < NS) {
            int st = starts[tid];
            int c  = starts[tid + 1] - st;
            seg_start_ws[b * NS + tid] = st;
            seg_count_ws[b * NS + tid] = c;
            out1[b * NS + tid] = (c > 0) ? 1.0f : 0.0f;
        }
        for (int t = tid; t <= NT; t += 256)
            out2[(size_t)b * (NT + 1) + t] = (float)bd[t];
    }

    // ---- pooling over my chunk ----
    const int s_first = sid_all[t0];
    float4 acc = make_float4(0.f, 0.f, 0.f, 0.f);
    int cur = s_first;

    auto flush = [&](int seg, const float4& a) {
        if (seg >= NS) return;
        const int st = starts[seg];
        const int c  = starts[seg + 1] - st;
        if (st >= t0 && st + c <= t0 + CH) {
            const float inv = 1.0f / (float)c;
            nt_store4(pooled + ((size_t)b * NS + seg) * ND + tid * 4,
                      a.x * inv, a.y * inv, a.z * inv, a.w * inv);
        } else {
            const int slot = (seg == s_first) ? 0 : 1;
            ((float4*)partial)[(((size_t)b * NQ + q) * 2 + slot) * (ND / 4) + tid] = a;
        }
    };

    auto consume = [&](int t, const float4& v) {
        int sg = sid_all[t];                  // uniform across block
        if (sg != cur) {
            flush(cur, acc);
            acc = make_float4(0.f, 0.f, 0.f, 0.f);
            cur = sg;
        }
        acc.x += v.x; acc.y += v.y; acc.z += v.z; acc.w += v.w;
    };

    // group 0 from prefetched registers
    consume(t0 + 0, p0); consume(t0 + 1, p1);
    consume(t0 + 2, p2); consume(t0 + 3, p3);
    consume(t0 + 4, p4); consume(t0 + 5, p5);
    consume(t0 + 6, p6); consume(t0 + 7, p7);

    for (int g = 1; g < CH / 8; ++g) {
        float4 v[8];
#pragma unroll
        for (int j = 0; j < 8; ++j)
            v[j] = xp[(size_t)(t0 + g * 8 + j) * (ND / 4)];
#pragma unroll
        for (int j = 0; j < 8; ++j)
            consume(t0 + g * 8 + j, v[j]);
    }
    flush(cur, acc);
}

// ---------------------------------------------------------------------------
// Kernel C: combine crossing-segment partials; zero empty rows.
// grid = (NS, NB), 256 threads.
// ---------------------------------------------------------------------------
__global__ __launch_bounds__(256)
void combine_kernel(const int* __restrict__ seg_start,    // [NB, NS]
                    const int* __restrict__ seg_count,    // [NB, NS]
                    const float* __restrict__ partial,    // [NB, NQ, 2, ND]
                    float* __restrict__ pooled)           // [NB, NS, ND]
{
    const int s   = blockIdx.x;
    const int b   = blockIdx.y;
    const int tid = threadIdx.x;

    const int st = seg_start[b * NS + s];
    const int c  = seg_count[b * NS + s];
    float* out = pooled + ((size_t)b * NS + s) * ND + tid * 4;

    if (c <= 0) {                             // empty segment: zero the row
        nt_store4(out, 0.f, 0.f, 0.f, 0.f);
        return;
    }
    const int q0 = st / CH;
    const int q1 = (st + c - 1) / CH;
    if (q0 == q1) return;                     // written by its chunk already

    const float4* pp = (const float4*)partial + tid;
    const int slot0 = (st == q0 * CH) ? 0 : 1;
    float4 a = pp[(((size_t)b * NQ + q0) * 2 + slot0) * (ND / 4)];
    for (int q = q0 + 1; q <= q1; ++q) {
        float4 v = pp[(((size_t)b * NQ + q) * 2 + 0) * (ND / 4)];
        a.x += v.x; a.y += v.y; a.z += v.z; a.w += v.w;
    }
    const float inv = 1.0f / (float)c;
    nt_store4(out, a.x * inv, a.y * inv, a.z * inv, a.w * inv);
}

// ---------------------------------------------------------------------------
extern "C" void kernel_launch(void* const* d_in, const int* in_sizes, int n_in,
                              void* d_out, int out_size, void* d_ws, size_t ws_size,
                              hipStream_t stream) {
    const float* x           = (const float*)d_in[0];       // [NB, NT, ND]
    const int*   in_boundary = (const int*)d_in[1];         // [NB, NT+1]

    float* pooled = (float*)d_out;                          // [NB, NS, ND]
    float* out1   = pooled + (size_t)NB * NS * ND;          // [NB, NS]
    float* out2   = out1 + (size_t)NB * NS;                 // [NB, NT+1]

    int*   seg_start = (int*)d_ws;                          // [NB, NS]
    int*   seg_count = seg_start + NB * NS;                 // [NB, NS]
    float* partial   = (float*)(seg_count + NB * NS);       // [NB, NQ, 2, ND]

    fused_pool_kernel<<<dim3(NQ, NB), 256, 0, stream>>>(
        x, in_boundary, seg_start, seg_count, partial, pooled, out1, out2);
    combine_kernel<<<dim3(NS, NB), 256, 0, stream>>>(seg_start, seg_count,
                                                     partial, pooled);
}

// Round 9
// 50.777 us; speedup vs baseline: 1.6115x; 1.0122x over previous
//
#include <hip/hip_runtime.h>

#define NB 32      // batch
#define NT 2048    // frames
#define ND 1024    // feature dim
#define NS 128     // max segments
#define CH 64      // frames per chunk
#define NQ (NT / CH)  // 32 chunks per batch row

typedef float f32x4 __attribute__((ext_vector_type(4)));  // clang-native vec4

__device__ __forceinline__ void nt_store4(float* p, float a, float b, float c, float d) {
    f32x4 v = {a, b, c, d};
    __builtin_nontemporal_store(v, (f32x4*)p);
}

// ---------------------------------------------------------------------------
// Fused kernel: per-block boundary scan (8 KB, L2-broadcast) + chunk pooling
// with two-group register double-buffering: group g+1's 8 loads are issued
// BEFORE group g is consumed, keeping 8-16 loads in flight per wave.
// grid = (NQ, NB), 256 threads.
// ---------------------------------------------------------------------------
__global__ __launch_bounds__(256, 4)
void fused_pool_kernel(const float* __restrict__ x,           // [NB, NT, ND]
                       const int* __restrict__ in_boundary,   // [NB, NT+1]
                       int* __restrict__ seg_start_ws,        // [NB, NS]
                       int* __restrict__ seg_count_ws,        // [NB, NS]
                       float* __restrict__ partial,           // [NB, NQ, 2, ND]
                       float* __restrict__ pooled,            // [NB, NS, ND]
                       float* __restrict__ out1,              // [NB, NS]
                       float* __restrict__ out2)              // [NB, NT+1]
{
    const int q    = blockIdx.x;
    const int b    = blockIdx.y;
    const int tid  = threadIdx.x;             // 256 threads = 4 waves
    const int lane = tid & 63;
    const int wid  = tid >> 6;
    const int t0   = q * CH;
    const int* bd  = in_boundary + (size_t)b * (NT + 1);

    const float4* xp = (const float4*)(x + (size_t)b * NT * ND) + tid;

#define LOADG(P, g)                                            \
    P##0 = xp[(size_t)(t0 + (g) * 8 + 0) * (ND / 4)];          \
    P##1 = xp[(size_t)(t0 + (g) * 8 + 1) * (ND / 4)];          \
    P##2 = xp[(size_t)(t0 + (g) * 8 + 2) * (ND / 4)];          \
    P##3 = xp[(size_t)(t0 + (g) * 8 + 3) * (ND / 4)];          \
    P##4 = xp[(size_t)(t0 + (g) * 8 + 4) * (ND / 4)];          \
    P##5 = xp[(size_t)(t0 + (g) * 8 + 5) * (ND / 4)];          \
    P##6 = xp[(size_t)(t0 + (g) * 8 + 6) * (ND / 4)];          \
    P##7 = xp[(size_t)(t0 + (g) * 8 + 7) * (ND / 4)]

#define CONSG(P, g)                                            \
    consume(t0 + (g) * 8 + 0, P##0);                           \
    consume(t0 + (g) * 8 + 1, P##1);                           \
    consume(t0 + (g) * 8 + 2, P##2);                           \
    consume(t0 + (g) * 8 + 3, P##3);                           \
    consume(t0 + (g) * 8 + 4, P##4);                           \
    consume(t0 + (g) * 8 + 5, P##5);                           \
    consume(t0 + (g) * 8 + 6, P##6);                           \
    consume(t0 + (g) * 8 + 7, P##7)

    float4 A0, A1, A2, A3, A4, A5, A6, A7;
    float4 B0, B1, B2, B3, B4, B5, B6, B7;

    // ---- issue group 0 loads; scan hides under their latency ----
    LOADG(A, 0);

    __shared__ int starts[NS + 1];
    __shared__ int wtot[4];
    __shared__ int sid_all[NT];

    for (int s = tid; s <= NS; s += 256) starts[s] = NT;  // default: no segment

    // ---- full-row boundary scan (thread tid owns frames tid*8..tid*8+7) ----
    const int f0 = tid * 8;
    int bv[8];
    int local = 0;
#pragma unroll
    for (int j = 0; j < 8; ++j) {
        int t = f0 + j;
        int bit = (t == 0) ? 1 : bd[t];       // force boundary at frame 0
        bv[j] = bit;
        local += bit;
    }

    int incl = local;
#pragma unroll
    for (int off = 1; off < 64; off <<= 1) {
        int n = __shfl_up(incl, off, 64);
        if (lane >= off) incl += n;
    }
    if (lane == 63) wtot[wid] = incl;
    __syncthreads();

    int wpref = 0;
#pragma unroll
    for (int w = 0; w < 4; ++w)
        if (w < wid) wpref += wtot[w];
    const int excl = wpref + incl - local;

    int run = excl;
#pragma unroll
    for (int j = 0; j < 8; ++j) {
        run += bv[j];
        int seg = run - 1;
        sid_all[f0 + j] = seg;
        if (bv[j] && seg <= NS) starts[seg] = f0 + j;
    }
    __syncthreads();

    // ---- pooling over my chunk, double-buffered ----
    const int s_first = sid_all[t0];
    float4 acc = make_float4(0.f, 0.f, 0.f, 0.f);
    int cur = s_first;

    auto flush = [&](int seg, const float4& a) {
        if (seg >= NS) return;
        const int st = starts[seg];
        const int c  = starts[seg + 1] - st;
        if (st >= t0 && st + c <= t0 + CH) {
            const float inv = 1.0f / (float)c;
            nt_store4(pooled + ((size_t)b * NS + seg) * ND + tid * 4,
                      a.x * inv, a.y * inv, a.z * inv, a.w * inv);
        } else {
            const int slot = (seg == s_first) ? 0 : 1;
            ((float4*)partial)[(((size_t)b * NQ + q) * 2 + slot) * (ND / 4) + tid] = a;
        }
    };

    auto consume = [&](int t, const float4& v) {
        int sg = sid_all[t];                  // LDS broadcast, uniform
        if (sg != cur) {
            flush(cur, acc);
            acc = make_float4(0.f, 0.f, 0.f, 0.f);
            cur = sg;
        }
        acc.x += v.x; acc.y += v.y; acc.z += v.z; acc.w += v.w;
    };

    LOADG(B, 1); CONSG(A, 0);                 // next group in flight while consuming
    LOADG(A, 2); CONSG(B, 1);
    LOADG(B, 3); CONSG(A, 2);
    LOADG(A, 4); CONSG(B, 3);
    LOADG(B, 5); CONSG(A, 4);
    LOADG(A, 6); CONSG(B, 5);
    LOADG(B, 7); CONSG(A, 6);
    CONSG(B, 7);
    flush(cur, acc);

    // ---- q==0 blocks emit scalar outputs + ws tables for combine (at end,
    //      so they don't delay the streaming loop) ----
    if (q == 0) {
        if (tid < NS) {
            int st = starts[tid];
            int c  = starts[tid + 1] - st;
            seg_start_ws[b * NS + tid] = st;
            seg_count_ws[b * NS + tid] = c;
            out1[b * NS + tid] = (c > 0) ? 1.0f : 0.0f;
        }
        for (int t = tid; t <= NT; t += 256)
            out2[(size_t)b * (NT + 1) + t] = (float)bd[t];
    }
#undef LOADG
#undef CONSG
}

// ---------------------------------------------------------------------------
// Kernel C: combine crossing-segment partials; zero empty rows.
// grid = (NS, NB), 256 threads.
// ---------------------------------------------------------------------------
__global__ __launch_bounds__(256)
void combine_kernel(const int* __restrict__ seg_start,    // [NB, NS]
                    const int* __restrict__ seg_count,    // [NB, NS]
                    const float* __restrict__ partial,    // [NB, NQ, 2, ND]
                    float* __restrict__ pooled)           // [NB, NS, ND]
{
    const int s   = blockIdx.x;
    const int b   = blockIdx.y;
    const int tid = threadIdx.x;

    const int st = seg_start[b * NS + s];
    const int c  = seg_count[b * NS + s];
    float* out = pooled + ((size_t)b * NS + s) * ND + tid * 4;

    if (c <= 0) {                             // empty segment: zero the row
        nt_store4(out, 0.f, 0.f, 0.f, 0.f);
        return;
    }
    const int q0 = st / CH;
    const int q1 = (st + c - 1) / CH;
    if (q0 == q1) return;                     // written by its chunk already

    const float4* pp = (const float4*)partial + tid;
    const int slot0 = (st == q0 * CH) ? 0 : 1;
    float4 a = pp[(((size_t)b * NQ + q0) * 2 + slot0) * (ND / 4)];
    for (int q = q0 + 1; q <= q1; ++q) {
        float4 v = pp[(((size_t)b * NQ + q) * 2 + 0) * (ND / 4)];
        a.x += v.x; a.y += v.y; a.z += v.z; a.w += v.w;
    }
    const float inv = 1.0f / (float)c;
    nt_store4(out, a.x * inv, a.y * inv, a.z * inv, a.w * inv);
}

// ---------------------------------------------------------------------------
extern "C" void kernel_launch(void* const* d_in, const int* in_sizes, int n_in,
                              void* d_out, int out_size, void* d_ws, size_t ws_size,
                              hipStream_t stream) {
    const float* x           = (const float*)d_in[0];       // [NB, NT, ND]
    const int*   in_boundary = (const int*)d_in[1];         // [NB, NT+1]

    float* pooled = (float*)d_out;                          // [NB, NS, ND]
    float* out1   = pooled + (size_t)NB * NS * ND;          // [NB, NS]
    float* out2   = out1 + (size_t)NB * NS;                 // [NB, NT+1]

    int*   seg_start = (int*)d_ws;                          // [NB, NS]
    int*   seg_count = seg_start + NB * NS;                 // [NB, NS]
    float* partial   = (float*)(seg_count + NB * NS);       // [NB, NQ, 2, ND]

    fused_pool_kernel<<<dim3(NQ, NB), 256, 0, stream>>>(
        x, in_boundary, seg_start, seg_count, partial, pooled, out1, out2);
    combine_kernel<<<dim3(NS, NB), 256, 0, stream>>>(seg_start, seg_count,
                                                     partial, pooled);
}